// Round 2
// 1328.088 us; speedup vs baseline: 1.0500x; 1.0500x over previous
//
#include <hip/hip_runtime.h>
#include <cstdint>
#include <cstddef>

#define B_    16
#define N_    170
#define T_    64
#define NT_   (N_ * T_)      /* 10880 tokens per batch */
#define C_    512
#define KH_   8

typedef unsigned short u16;
typedef float  f32x4  __attribute__((ext_vector_type(4)));
typedef short  bf16x8 __attribute__((ext_vector_type(8)));

__device__ __forceinline__ u16 f2bf(float f) {
  union { float f; unsigned u; } v; v.f = f;
  unsigned r = v.u + 0x7fffu + ((v.u >> 16) & 1u);   // RNE
  return (u16)(r >> 16);
}

#define GLDS16(g, l) \
  __builtin_amdgcn_global_load_lds((const __attribute__((address_space(1))) void*)(g), \
                                   (__attribute__((address_space(3))) void*)(l), 16, 0, 0)

// bijective XCD-chunk swizzle (m204): orig%8 = hw XCD, chunks of n/8 per XCD
__device__ __forceinline__ int xcd_swz(int orig, int n) {
  int q = n >> 3, r = n & 7;
  int xcd = orig & 7, idx = orig >> 3;
  return (xcd < r ? xcd * (q + 1) : r * (q + 1) + (xcd - r) * q) + idx;
}

// ---------------------------------------------------------------------------
// Weights fp32 -> bf16 into concatenated wqkv [1536][512] + wo [512][512];
// also builds concatenated bias bqkv[1536].
// ---------------------------------------------------------------------------
__global__ __launch_bounds__(256) void wconv(const float* __restrict__ wq, const float* __restrict__ wk,
                                             const float* __restrict__ wv, const float* __restrict__ wo,
                                             const float* __restrict__ bq, const float* __restrict__ bk,
                                             const float* __restrict__ bv,
                                             u16* __restrict__ oq, u16* __restrict__ ok,
                                             u16* __restrict__ ov, u16* __restrict__ oo,
                                             float* __restrict__ obias) {
  int idx = blockIdx.x * 256 + threadIdx.x;        // 262144 threads, 4 floats each
  int mat = idx >> 16;
  int off = (idx & 65535) * 4;
  const float* s = (mat == 0) ? wq : (mat == 1) ? wk : (mat == 2) ? wv : wo;
  u16* d = (mat == 0) ? oq : (mat == 1) ? ok : (mat == 2) ? ov : oo;
  float4 v = *(const float4*)(s + off);
  u16 o[4] = { f2bf(v.x), f2bf(v.y), f2bf(v.z), f2bf(v.w) };
  *(uint2*)(d + off) = *(uint2*)o;
  if (idx < 1536)
    obias[idx] = (idx < 512) ? bq[idx] : (idx < 1024) ? bk[idx - 512] : bv[idx - 1024];
}

// ---------------------------------------------------------------------------
// concat(x, tem) on channel dim + transpose to token-major bf16:
// xin_tm[b][nt][c] (c contiguous). 64x64 tile per block via LDS.
// ---------------------------------------------------------------------------
__global__ __launch_bounds__(256) void concat_tr(const float* __restrict__ x,
                                                 const float* __restrict__ tem,
                                                 u16* __restrict__ xin_tm) {
  __shared__ u16 tile[64 * 72];
  int mt = blockIdx.x, ct = blockIdx.y, b = blockIdx.z;
  const float* src = (ct < 4) ? (x   + ((size_t)b * 256 + (size_t)ct * 64) * NT_)
                              : (tem + ((size_t)b * 256 + (size_t)(ct - 4) * 64) * NT_);
  int m0 = mt * 64;
  int tid = threadIdx.x;
  for (int g = tid; g < 1024; g += 256) {
    int row = g >> 4, part = (g & 15) * 4;
    float4 v = *(const float4*)(src + (size_t)row * NT_ + m0 + part);
    u16* t = &tile[row * 72 + part];
    t[0] = f2bf(v.x); t[1] = f2bf(v.y); t[2] = f2bf(v.z); t[3] = f2bf(v.w);
  }
  __syncthreads();
  for (int h = tid; h < 512; h += 256) {
    int mm = h >> 3, part = (h & 7) * 8;
    u16 vals[8];
#pragma unroll
    for (int e = 0; e < 8; e++) vals[e] = tile[(part + e) * 72 + mm];
    *(uint4*)(xin_tm + ((size_t)(b * NT_ + m0 + mm)) * 512 + ct * 64 + part) = *(uint4*)vals;
  }
}

// ---------------------------------------------------------------------------
// C[M][N] = sum_k A[m][k]*B[n][k]  (both operands K-contiguous, bf16)
// MODE 0: fused QKV. B = wqkv[1536][512]; col-tile ct selects dest matrix
//         (q/k/v token-major, consecutive buffers via matStride). bf16 out,
//         bias by global col, LDS-bounced vectorized stores.
// MODE 2: f32 out + relu, bias indexed by row (final y), scalar stores
//         (already 64B-sector aligned).
// 128x128 tile, BK=32, 4 waves, 16x16x32 MFMA, global_load_lds staging,
// bijective XCD swizzle for operand-panel L2 reuse.
// ---------------------------------------------------------------------------
template <int MODE>
__global__ __launch_bounds__(256) void gemm_bt(
    const u16* __restrict__ A, int lda, size_t aBatch,
    const u16* __restrict__ Bm, int ldb, size_t bBatch,
    void* __restrict__ Cv, int ldc, size_t cBatch, size_t matStride,
    const float* __restrict__ bias, int K) {
  constexpr int NBLK  = (MODE == 0) ? 1020 : 340;   // blocks per batch-slice
  constexpr int NFAST = (MODE == 0) ? 12 : 4;       // fast dim shares the reused panel
  __shared__ u16 As[128 * 32];
  __shared__ u16 Bs[128 * 32];
  __shared__ u16 cst[(MODE == 0) ? 128 * 136 : 16];

  int b = blockIdx.z;
  int lin = xcd_swz(blockIdx.x, NBLK);
  int fast = lin % NFAST, slow = lin / NFAST;
  int bxT = (MODE == 0) ? fast : slow;              // B-row tile index
  int ayT = (MODE == 0) ? slow : fast;              // A-row tile index
  int rowA0 = ayT * 128, rowB0 = bxT * 128;

  const u16* Ab = A + (size_t)b * aBatch;
  const u16* Bb = Bm + (size_t)b * bBatch;
  int tid = threadIdx.x;
  int lane = tid & 63, w = tid >> 6;
  int quad = lane >> 4, l15 = lane & 15;
  int wr = (w >> 1) * 64, wc = (w & 1) * 64;

  f32x4 acc[4][4];
#pragma unroll
  for (int i = 0; i < 4; i++)
#pragma unroll
    for (int j = 0; j < 4; j++) acc[i][j] = (f32x4){0.f, 0.f, 0.f, 0.f};

  for (int k0 = 0; k0 < K; k0 += 32) {
#pragma unroll
    for (int r = 0; r < 2; r++) {
      int chunk = tid + r * 256;             // 512 x 16B chunks per tile
      int row = chunk >> 2, kk = (chunk & 3) * 8;
      const u16* ga = Ab + (size_t)(rowA0 + row) * lda + k0 + kk;
      GLDS16(ga, &As[(r * 256 + w * 64) * 8]);   // wave-uniform LDS base + lane*16
      const u16* gb = Bb + (size_t)(rowB0 + row) * ldb + k0 + kk;
      GLDS16(gb, &Bs[(r * 256 + w * 64) * 8]);
    }
    __syncthreads();
    bf16x8 af[4], bfr[4];
#pragma unroll
    for (int i = 0; i < 4; i++) af[i]  = *(const bf16x8*)&As[(wr + i * 16 + l15) * 32 + quad * 8];
#pragma unroll
    for (int j = 0; j < 4; j++) bfr[j] = *(const bf16x8*)&Bs[(wc + j * 16 + l15) * 32 + quad * 8];
#pragma unroll
    for (int i = 0; i < 4; i++)
#pragma unroll
      for (int j = 0; j < 4; j++)
        acc[i][j] = __builtin_amdgcn_mfma_f32_16x16x32_bf16(af[i], bfr[j], acc[i][j], 0, 0, 0);
    __syncthreads();
  }

  int gr0 = rowA0 + wr, gc0 = rowB0 + wc;
  if constexpr (MODE == 0) {
    int mat  = bxT >> 2;               // 0=q 1=k 2=v
    int colb = (bxT & 3) * 128;        // col base within dest matrix
    // acc -> LDS (bias applied, bf16), stride 136 pads conflicts to ~2-way
#pragma unroll
    for (int j = 0; j < 4; j++) {
      int lc = wc + j * 16 + l15;
      float bj = bias[rowB0 + lc];
#pragma unroll
      for (int i = 0; i < 4; i++) {
        int lr = wr + i * 16 + quad * 4;
#pragma unroll
        for (int r = 0; r < 4; r++)
          cst[(lr + r) * 136 + lc] = f2bf(acc[i][j][r] + bj);
      }
    }
    __syncthreads();
    u16* C = (u16*)Cv + (size_t)b * cBatch + (size_t)mat * matStride
           + (size_t)rowA0 * ldc + colb;
#pragma unroll
    for (int it = 0; it < 8; it++) {
      int chunk = tid + it * 256;            // 2048 x 16B chunks
      int row = chunk >> 4, cc = (chunk & 15) * 8;
      *(uint4*)(C + (size_t)row * ldc + cc) = *(const uint4*)&cst[row * 136 + cc];
    }
  } else {
    float* C = (float*)Cv + (size_t)b * cBatch;
#pragma unroll
    for (int i = 0; i < 4; i++)
#pragma unroll
      for (int r = 0; r < 4; r++) {
        int R = gr0 + i * 16 + quad * 4 + r;
        float br = bias[R];
#pragma unroll
        for (int j = 0; j < 4; j++) {
          float v = acc[i][j][r] + br;
          C[(size_t)R * ldc + gc0 + j * 16 + l15] = fmaxf(v, 0.f);
        }
      }
  }
}

// ---------------------------------------------------------------------------
// Causal attention per (head, b, n): S=QK^T/8, mask, softmax, O=PV.
// q/k/v all token-major [t][512] (head slice at kh*64). V is transposed
// during LDS staging into vsh[d][s] (stride 66: transpose writes ~2-way,
// PV B-fragments read as 4x ds_read_b32). Output token-major bf16.
// ---------------------------------------------------------------------------
__global__ __launch_bounds__(256) void attn(const u16* __restrict__ q_tm,
                                            const u16* __restrict__ k_tm,
                                            const u16* __restrict__ v_tm,
                                            u16* __restrict__ ao_tm) {
  __shared__ u16 qsh[64 * 72], ksh[64 * 72], psh[64 * 72];
  __shared__ u16 vsh[64 * 66];
  int n = blockIdx.x, kh = blockIdx.y, b = blockIdx.z;
  int tid = threadIdx.x, lane = tid & 63, w = tid >> 6;
  int quad = lane >> 4, l15 = lane & 15;

  const u16* qbase = q_tm + ((size_t)(b * NT_ + n * 64)) * 512 + kh * 64;
  const u16* kbase = k_tm + ((size_t)(b * NT_ + n * 64)) * 512 + kh * 64;
  const u16* vbase = v_tm + ((size_t)(b * NT_ + n * 64)) * 512 + kh * 64;

  for (int g = tid; g < 512; g += 256) {
    int row = g >> 3, part = (g & 7) * 8;
    *(uint4*)&qsh[row * 72 + part] = *(const uint4*)(qbase + (size_t)row * 512 + part);
    *(uint4*)&ksh[row * 72 + part] = *(const uint4*)(kbase + (size_t)row * 512 + part);
    u16 tv[8];
    *(uint4*)tv = *(const uint4*)(vbase + (size_t)row * 512 + part);
#pragma unroll
    for (int e = 0; e < 8; e++) vsh[(part + e) * 66 + row] = tv[e];   // vsh[d][s]
  }
  __syncthreads();

  // S rows [16w, 16w+16)
  f32x4 sacc[4];
#pragma unroll
  for (int j = 0; j < 4; j++) sacc[j] = (f32x4){0.f, 0.f, 0.f, 0.f};
  bf16x8 aq[2];
#pragma unroll
  for (int kc = 0; kc < 2; kc++)
    aq[kc] = *(const bf16x8*)&qsh[(w * 16 + l15) * 72 + kc * 32 + quad * 8];
#pragma unroll
  for (int j = 0; j < 4; j++)
#pragma unroll
    for (int kc = 0; kc < 2; kc++) {
      bf16x8 bk = *(const bf16x8*)&ksh[(j * 16 + l15) * 72 + kc * 32 + quad * 8];
      sacc[j] = __builtin_amdgcn_mfma_f32_16x16x32_bf16(aq[kc], bk, sacc[j], 0, 0, 0);
    }

  // mask + softmax; row t = 16w + quad*4 + r, col s = 16j + l15
  float pv[4][4];
#pragma unroll
  for (int r = 0; r < 4; r++) {
    int t = w * 16 + quad * 4 + r;
    float m = -3.4e38f;
#pragma unroll
    for (int j = 0; j < 4; j++) {
      int s = j * 16 + l15;
      float v = sacc[j][r] * 0.125f;
      if (s > t) v = -32767.0f;
      pv[j][r] = v;
      m = fmaxf(m, v);
    }
#pragma unroll
    for (int off = 1; off < 16; off <<= 1) m = fmaxf(m, __shfl_xor(m, off, 16));
    float sum = 0.f;
#pragma unroll
    for (int j = 0; j < 4; j++) {
      float e = __expf(pv[j][r] - m);
      pv[j][r] = e;
      sum += e;
    }
#pragma unroll
    for (int off = 1; off < 16; off <<= 1) sum += __shfl_xor(sum, off, 16);
    float inv = 1.f / sum;
#pragma unroll
    for (int j = 0; j < 4; j++)
      psh[(size_t)t * 72 + j * 16 + l15] = f2bf(pv[j][r] * inv);
  }
  // PV: same wave reads only its own 16 rows of psh -> no barrier needed
  f32x4 oacc[4];
#pragma unroll
  for (int j = 0; j < 4; j++) oacc[j] = (f32x4){0.f, 0.f, 0.f, 0.f};
  bf16x8 ap[2];
#pragma unroll
  for (int kc = 0; kc < 2; kc++)
    ap[kc] = *(const bf16x8*)&psh[(w * 16 + l15) * 72 + kc * 32 + quad * 8];
#pragma unroll
  for (int dj = 0; dj < 4; dj++)
#pragma unroll
    for (int kc = 0; kc < 2; kc++) {
      bf16x8 bv;
      {
        const unsigned* vp = (const unsigned*)&vsh[(dj * 16 + l15) * 66 + kc * 32 + quad * 8];
        unsigned* bp = (unsigned*)&bv;
        bp[0] = vp[0]; bp[1] = vp[1]; bp[2] = vp[2]; bp[3] = vp[3];
      }
      oacc[dj] = __builtin_amdgcn_mfma_f32_16x16x32_bf16(ap[kc], bv, oacc[dj], 0, 0, 0);
    }

  u16* ob = ao_tm + ((size_t)(b * NT_ + n * 64)) * 512 + kh * 64;
#pragma unroll
  for (int dj = 0; dj < 4; dj++)
#pragma unroll
    for (int r = 0; r < 4; r++) {
      int t = w * 16 + quad * 4 + r, d = dj * 16 + l15;
      ob[(size_t)t * 512 + d] = f2bf(oacc[dj][r]);
    }
}

// ---------------------------------------------------------------------------
extern "C" void kernel_launch(void* const* d_in, const int* in_sizes, int n_in,
                              void* d_out, int out_size, void* d_ws, size_t ws_size,
                              hipStream_t stream) {
  const float* x   = (const float*)d_in[0];
  const float* tem = (const float*)d_in[1];
  const float* Wq  = (const float*)d_in[2];
  const float* bq  = (const float*)d_in[3];
  const float* Wk  = (const float*)d_in[4];
  const float* bk  = (const float*)d_in[5];
  const float* Wv  = (const float*)d_in[6];
  const float* bv  = (const float*)d_in[7];
  const float* Wo  = (const float*)d_in[8];
  const float* bo  = (const float*)d_in[9];
  float* out = (float*)d_out;

  const size_t E = (size_t)B_ * 512 * NT_;   // 89,128,960 elems per bf16 tensor
  u16* xin_tm = (u16*)d_ws;                  // [b][nt][512]; later reused as ao_tm
  u16* q_tm   = xin_tm + E;                  // [b][nt][512]
  u16* k_tm   = q_tm + E;                    // [b][nt][512]
  u16* v_tm   = k_tm + E;                    // [b][nt][512] (token-major now)
  u16* wqkv   = v_tm + E;                    // [1536][512]
  u16* wob    = wqkv + 786432;               // [512][512]
  float* bqkv = (float*)(wob + 262144);      // [1536]
  u16* ao_tm  = xin_tm;                      // alias: xin dead after QKV GEMM

  const size_t sBNT = (size_t)NT_ * 512;     // per-batch stride (token-major)

  wconv<<<1024, 256, 0, stream>>>(Wq, Wk, Wv, Wo, bq, bk, bv,
                                  wqkv, wqkv + 262144, wqkv + 524288, wob, bqkv);
  concat_tr<<<dim3(N_, 8, B_), 256, 0, stream>>>(x, tem, xin_tm);

  // Fused QKV: C[m][o] over o in [0,1536), dest selected per col-tile.
  gemm_bt<0><<<dim3(1020, 1, B_), 256, 0, stream>>>(xin_tm, 512, sBNT,
                                                    wqkv, 512, (size_t)0,
                                                    q_tm, 512, sBNT, E, bqkv, 512);

  attn<<<dim3(N_, KH_, B_), 256, 0, stream>>>(q_tm, k_tm, v_tm, ao_tm);

  // Y = relu(Wo . ao + bo), fp32 channel-major straight to d_out
  gemm_bt<2><<<dim3(340, 1, B_), 256, 0, stream>>>(wob, 512, (size_t)0,
                                                   ao_tm, 512, sBNT,
                                                   out, NT_, (size_t)512 * NT_, 0, bo, 512);
}

// Round 3
// 1257.066 us; speedup vs baseline: 1.1094x; 1.0565x over previous
//
#include <hip/hip_runtime.h>
#include <cstdint>
#include <cstddef>

#define B_    16
#define N_    170
#define T_    64
#define NT_   (N_ * T_)      /* 10880 tokens per batch */
#define C_    512
#define KH_   8

typedef unsigned short u16;
typedef float  f32x4  __attribute__((ext_vector_type(4)));
typedef short  bf16x8 __attribute__((ext_vector_type(8)));

__device__ __forceinline__ u16 f2bf(float f) {
  union { float f; unsigned u; } v; v.f = f;
  unsigned r = v.u + 0x7fffu + ((v.u >> 16) & 1u);   // RNE
  return (u16)(r >> 16);
}

#define GLDS16(g, l) \
  __builtin_amdgcn_global_load_lds((const __attribute__((address_space(1))) void*)(g), \
                                   (__attribute__((address_space(3))) void*)(l), 16, 0, 0)

// bijective XCD-chunk swizzle (m204): orig%8 = hw XCD, chunks of n/8 per XCD
__device__ __forceinline__ int xcd_swz(int orig, int n) {
  int q = n >> 3, r = n & 7;
  int xcd = orig & 7, idx = orig >> 3;
  return (xcd < r ? xcd * (q + 1) : r * (q + 1) + (xcd - r) * q) + idx;
}

// ---------------------------------------------------------------------------
// Weights fp32 -> bf16 into concatenated wqkv [1536][512] + wo [512][512];
// also builds concatenated bias bqkv[1536].
// ---------------------------------------------------------------------------
__global__ __launch_bounds__(256) void wconv(const float* __restrict__ wq, const float* __restrict__ wk,
                                             const float* __restrict__ wv, const float* __restrict__ wo,
                                             const float* __restrict__ bq, const float* __restrict__ bk,
                                             const float* __restrict__ bv,
                                             u16* __restrict__ oq, u16* __restrict__ ok,
                                             u16* __restrict__ ov, u16* __restrict__ oo,
                                             float* __restrict__ obias) {
  int idx = blockIdx.x * 256 + threadIdx.x;        // 262144 threads, 4 floats each
  int mat = idx >> 16;
  int off = (idx & 65535) * 4;
  const float* s = (mat == 0) ? wq : (mat == 1) ? wk : (mat == 2) ? wv : wo;
  u16* d = (mat == 0) ? oq : (mat == 1) ? ok : (mat == 2) ? ov : oo;
  float4 v = *(const float4*)(s + off);
  u16 o[4] = { f2bf(v.x), f2bf(v.y), f2bf(v.z), f2bf(v.w) };
  *(uint2*)(d + off) = *(uint2*)o;
  if (idx < 1536)
    obias[idx] = (idx < 512) ? bq[idx] : (idx < 1024) ? bk[idx - 512] : bv[idx - 1024];
}

// ---------------------------------------------------------------------------
// concat(x, tem) on channel dim + transpose to token-major bf16:
// xin_tm[b][nt][c] (c contiguous). 64x64 tile per block via LDS.
// ---------------------------------------------------------------------------
__global__ __launch_bounds__(256) void concat_tr(const float* __restrict__ x,
                                                 const float* __restrict__ tem,
                                                 u16* __restrict__ xin_tm) {
  __shared__ u16 tile[64 * 72];
  int mt = blockIdx.x, ct = blockIdx.y, b = blockIdx.z;
  const float* src = (ct < 4) ? (x   + ((size_t)b * 256 + (size_t)ct * 64) * NT_)
                              : (tem + ((size_t)b * 256 + (size_t)(ct - 4) * 64) * NT_);
  int m0 = mt * 64;
  int tid = threadIdx.x;
  for (int g = tid; g < 1024; g += 256) {
    int row = g >> 4, part = (g & 15) * 4;
    float4 v = *(const float4*)(src + (size_t)row * NT_ + m0 + part);
    u16* t = &tile[row * 72 + part];
    t[0] = f2bf(v.x); t[1] = f2bf(v.y); t[2] = f2bf(v.z); t[3] = f2bf(v.w);
  }
  __syncthreads();
  for (int h = tid; h < 512; h += 256) {
    int mm = h >> 3, part = (h & 7) * 8;
    u16 vals[8];
#pragma unroll
    for (int e = 0; e < 8; e++) vals[e] = tile[(part + e) * 72 + mm];
    *(uint4*)(xin_tm + ((size_t)(b * NT_ + m0 + mm)) * 512 + ct * 64 + part) = *(uint4*)vals;
  }
}

// ---------------------------------------------------------------------------
// C[M][N] = sum_k A[m][k]*B[n][k]  (both operands K-contiguous, bf16)
// MODE 0: fused QKV (bf16 out, bias by col, LDS-bounced vectorized stores).
// MODE 2: f32 out + relu, bias by row (final y), direct stores.
// 128x128 tile, BK=32, 4 waves, 16x16x32 MFMA.
// 2-phase pipeline: double-buffered global_load_lds staging, next tile's
// loads issued BEFORE current tile's ds_read+MFMA; ONE barrier per K-step.
// LDS: stage double-buffer (32 KB); MODE0 epilogue cst (34.8 KB) aliases it
// -> 4 blocks/CU (MODE0), 5 blocks/CU (MODE2).
// Chunk-permute swizzle: LDS slot (row, q) holds global k-chunk q^(row&3)
// (involution, applied on GLDS source addr + ds_read addr) -> 8-way
// bank conflict reduced to 4-way; within-row 64B coalescing preserved.
// ---------------------------------------------------------------------------
template <int MODE>
__global__ __launch_bounds__(256) void gemm_bt(
    const u16* __restrict__ A, int lda, size_t aBatch,
    const u16* __restrict__ Bm, int ldb, size_t bBatch,
    void* __restrict__ Cv, int ldc, size_t cBatch, size_t matStride,
    const float* __restrict__ bias, int K) {
  constexpr int NBLK  = (MODE == 0) ? 1020 : 340;   // blocks per batch-slice
  constexpr int NFAST = (MODE == 0) ? 12 : 4;       // fast dim shares the reused panel
  // stage buf b: As at b*8192, Bs at b*8192+4096 (u16 units). 2 bufs = 16384 u16.
  // MODE0 epilogue cst[128*136] = 17408 u16 aliases the whole region.
  __shared__ u16 lds[(MODE == 0) ? 17408 : 16384];

  int b = blockIdx.z;
  int lin = xcd_swz(blockIdx.x, NBLK);
  int fast = lin % NFAST, slow = lin / NFAST;
  int bxT = (MODE == 0) ? fast : slow;              // B-row tile index
  int ayT = (MODE == 0) ? slow : fast;              // A-row tile index
  int rowA0 = ayT * 128, rowB0 = bxT * 128;

  const u16* Ab = A + (size_t)b * aBatch;
  const u16* Bb = Bm + (size_t)b * bBatch;
  int tid = threadIdx.x;
  int lane = tid & 63, w = tid >> 6;
  int quad = lane >> 4, l15 = lane & 15;
  int wr = (w >> 1) * 64, wc = (w & 1) * 64;

  f32x4 acc[4][4];
#pragma unroll
  for (int i = 0; i < 4; i++)
#pragma unroll
    for (int j = 0; j < 4; j++) acc[i][j] = (f32x4){0.f, 0.f, 0.f, 0.f};

  // stage one 128x32 A-tile + B-tile into buffer `buf` (chunk-permuted source)
  auto stage = [&](int k0, int buf) {
    u16* As = lds + buf * 8192;
    u16* Bs = As + 4096;
#pragma unroll
    for (int r = 0; r < 2; r++) {
      int chunk = tid + r * 256;             // 512 x 16B chunks per tile
      int row = chunk >> 2;
      int kk = ((chunk & 3) ^ (row & 3)) * 8;            // permuted k-chunk
      const u16* ga = Ab + (size_t)(rowA0 + row) * lda + k0 + kk;
      GLDS16(ga, &As[(r * 256 + w * 64) * 8]);   // wave-uniform base + lane*16
      const u16* gb = Bb + (size_t)(rowB0 + row) * ldb + k0 + kk;
      GLDS16(gb, &Bs[(r * 256 + w * 64) * 8]);
    }
  };

  int nt = K >> 5;                           // K-steps of 32
  stage(0, 0);
  __syncthreads();
  for (int t = 0; t < nt; t++) {
    if (t + 1 < nt) stage((t + 1) << 5, (t + 1) & 1);    // prefetch next tile
    const u16* As = lds + (t & 1) * 8192;
    const u16* Bs = As + 4096;
    bf16x8 af[4], bfr[4];
    int pq = quad ^ (l15 & 3);               // physical chunk after swizzle
#pragma unroll
    for (int i = 0; i < 4; i++) af[i]  = *(const bf16x8*)&As[((wr + i * 16 + l15) * 4 + pq) * 8];
#pragma unroll
    for (int j = 0; j < 4; j++) bfr[j] = *(const bf16x8*)&Bs[((wc + j * 16 + l15) * 4 + pq) * 8];
#pragma unroll
    for (int i = 0; i < 4; i++)
#pragma unroll
      for (int j = 0; j < 4; j++)
        acc[i][j] = __builtin_amdgcn_mfma_f32_16x16x32_bf16(af[i], bfr[j], acc[i][j], 0, 0, 0);
    __syncthreads();                         // drains lgkm (reads) + vm (prefetch)
  }

  int gr0 = rowA0 + wr, gc0 = rowB0 + wc;
  if constexpr (MODE == 0) {
    int mat  = bxT >> 2;               // 0=q 1=k 2=v
    int colb = (bxT & 3) * 128;        // col base within dest matrix
    u16* cst = lds;                    // stage buffers dead after final barrier
    // acc -> LDS (bias applied, bf16), stride 136 pads conflicts to ~2-way
#pragma unroll
    for (int j = 0; j < 4; j++) {
      int lc = wc + j * 16 + l15;
      float bj = bias[rowB0 + lc];
#pragma unroll
      for (int i = 0; i < 4; i++) {
        int lr = wr + i * 16 + quad * 4;
#pragma unroll
        for (int r = 0; r < 4; r++)
          cst[(lr + r) * 136 + lc] = f2bf(acc[i][j][r] + bj);
      }
    }
    __syncthreads();
    u16* C = (u16*)Cv + (size_t)b * cBatch + (size_t)mat * matStride
           + (size_t)rowA0 * ldc + colb;
#pragma unroll
    for (int it = 0; it < 8; it++) {
      int chunk = tid + it * 256;            // 2048 x 16B chunks
      int row = chunk >> 4, cc = (chunk & 15) * 8;
      *(uint4*)(C + (size_t)row * ldc + cc) = *(const uint4*)&cst[row * 136 + cc];
    }
  } else {
    float* C = (float*)Cv + (size_t)b * cBatch;
#pragma unroll
    for (int i = 0; i < 4; i++)
#pragma unroll
      for (int r = 0; r < 4; r++) {
        int R = gr0 + i * 16 + quad * 4 + r;
        float br = bias[R];
#pragma unroll
        for (int j = 0; j < 4; j++) {
          float v = acc[i][j][r] + br;
          C[(size_t)R * ldc + gc0 + j * 16 + l15] = fmaxf(v, 0.f);
        }
      }
  }
}

// ---------------------------------------------------------------------------
// Causal attention per (head, b, n): S=QK^T/8, mask, softmax, O=PV.
// q/k/v all token-major [t][512] (head slice at kh*64). V is transposed
// during LDS staging into vsh[d][s] (stride 66). Output token-major bf16.
// ---------------------------------------------------------------------------
__global__ __launch_bounds__(256) void attn(const u16* __restrict__ q_tm,
                                            const u16* __restrict__ k_tm,
                                            const u16* __restrict__ v_tm,
                                            u16* __restrict__ ao_tm) {
  __shared__ u16 qsh[64 * 72], ksh[64 * 72], psh[64 * 72];
  __shared__ u16 vsh[64 * 66];
  int n = blockIdx.x, kh = blockIdx.y, b = blockIdx.z;
  int tid = threadIdx.x, lane = tid & 63, w = tid >> 6;
  int quad = lane >> 4, l15 = lane & 15;

  const u16* qbase = q_tm + ((size_t)(b * NT_ + n * 64)) * 512 + kh * 64;
  const u16* kbase = k_tm + ((size_t)(b * NT_ + n * 64)) * 512 + kh * 64;
  const u16* vbase = v_tm + ((size_t)(b * NT_ + n * 64)) * 512 + kh * 64;

  for (int g = tid; g < 512; g += 256) {
    int row = g >> 3, part = (g & 7) * 8;
    *(uint4*)&qsh[row * 72 + part] = *(const uint4*)(qbase + (size_t)row * 512 + part);
    *(uint4*)&ksh[row * 72 + part] = *(const uint4*)(kbase + (size_t)row * 512 + part);
    u16 tv[8];
    *(uint4*)tv = *(const uint4*)(vbase + (size_t)row * 512 + part);
#pragma unroll
    for (int e = 0; e < 8; e++) vsh[(part + e) * 66 + row] = tv[e];   // vsh[d][s]
  }
  __syncthreads();

  // S rows [16w, 16w+16)
  f32x4 sacc[4];
#pragma unroll
  for (int j = 0; j < 4; j++) sacc[j] = (f32x4){0.f, 0.f, 0.f, 0.f};
  bf16x8 aq[2];
#pragma unroll
  for (int kc = 0; kc < 2; kc++)
    aq[kc] = *(const bf16x8*)&qsh[(w * 16 + l15) * 72 + kc * 32 + quad * 8];
#pragma unroll
  for (int j = 0; j < 4; j++)
#pragma unroll
    for (int kc = 0; kc < 2; kc++) {
      bf16x8 bk = *(const bf16x8*)&ksh[(j * 16 + l15) * 72 + kc * 32 + quad * 8];
      sacc[j] = __builtin_amdgcn_mfma_f32_16x16x32_bf16(aq[kc], bk, sacc[j], 0, 0, 0);
    }

  // mask + softmax; row t = 16w + quad*4 + r, col s = 16j + l15
  float pv[4][4];
#pragma unroll
  for (int r = 0; r < 4; r++) {
    int t = w * 16 + quad * 4 + r;
    float m = -3.4e38f;
#pragma unroll
    for (int j = 0; j < 4; j++) {
      int s = j * 16 + l15;
      float v = sacc[j][r] * 0.125f;
      if (s > t) v = -32767.0f;
      pv[j][r] = v;
      m = fmaxf(m, v);
    }
#pragma unroll
    for (int off = 1; off < 16; off <<= 1) m = fmaxf(m, __shfl_xor(m, off, 16));
    float sum = 0.f;
#pragma unroll
    for (int j = 0; j < 4; j++) {
      float e = __expf(pv[j][r] - m);
      pv[j][r] = e;
      sum += e;
    }
#pragma unroll
    for (int off = 1; off < 16; off <<= 1) sum += __shfl_xor(sum, off, 16);
    float inv = 1.f / sum;
#pragma unroll
    for (int j = 0; j < 4; j++)
      psh[(size_t)t * 72 + j * 16 + l15] = f2bf(pv[j][r] * inv);
  }
  // PV: same wave reads only its own 16 rows of psh -> no barrier needed
  f32x4 oacc[4];
#pragma unroll
  for (int j = 0; j < 4; j++) oacc[j] = (f32x4){0.f, 0.f, 0.f, 0.f};
  bf16x8 ap[2];
#pragma unroll
  for (int kc = 0; kc < 2; kc++)
    ap[kc] = *(const bf16x8*)&psh[(w * 16 + l15) * 72 + kc * 32 + quad * 8];
#pragma unroll
  for (int dj = 0; dj < 4; dj++)
#pragma unroll
    for (int kc = 0; kc < 2; kc++) {
      bf16x8 bv;
      {
        const unsigned* vp = (const unsigned*)&vsh[(dj * 16 + l15) * 66 + kc * 32 + quad * 8];
        unsigned* bp = (unsigned*)&bv;
        bp[0] = vp[0]; bp[1] = vp[1]; bp[2] = vp[2]; bp[3] = vp[3];
      }
      oacc[dj] = __builtin_amdgcn_mfma_f32_16x16x32_bf16(ap[kc], bv, oacc[dj], 0, 0, 0);
    }

  u16* ob = ao_tm + ((size_t)(b * NT_ + n * 64)) * 512 + kh * 64;
#pragma unroll
  for (int dj = 0; dj < 4; dj++)
#pragma unroll
    for (int r = 0; r < 4; r++) {
      int t = w * 16 + quad * 4 + r, d = dj * 16 + l15;
      ob[(size_t)t * 512 + d] = f2bf(oacc[dj][r]);
    }
}

// ---------------------------------------------------------------------------
extern "C" void kernel_launch(void* const* d_in, const int* in_sizes, int n_in,
                              void* d_out, int out_size, void* d_ws, size_t ws_size,
                              hipStream_t stream) {
  const float* x   = (const float*)d_in[0];
  const float* tem = (const float*)d_in[1];
  const float* Wq  = (const float*)d_in[2];
  const float* bq  = (const float*)d_in[3];
  const float* Wk  = (const float*)d_in[4];
  const float* bk  = (const float*)d_in[5];
  const float* Wv  = (const float*)d_in[6];
  const float* bv  = (const float*)d_in[7];
  const float* Wo  = (const float*)d_in[8];
  const float* bo  = (const float*)d_in[9];
  float* out = (float*)d_out;

  const size_t E = (size_t)B_ * 512 * NT_;   // 89,128,960 elems per bf16 tensor
  u16* xin_tm = (u16*)d_ws;                  // [b][nt][512]; later reused as ao_tm
  u16* q_tm   = xin_tm + E;                  // [b][nt][512]
  u16* k_tm   = q_tm + E;                    // [b][nt][512]
  u16* v_tm   = k_tm + E;                    // [b][nt][512] (token-major)
  u16* wqkv   = v_tm + E;                    // [1536][512]
  u16* wob    = wqkv + 786432;               // [512][512]
  float* bqkv = (float*)(wob + 262144);      // [1536]
  u16* ao_tm  = xin_tm;                      // alias: xin dead after QKV GEMM

  const size_t sBNT = (size_t)NT_ * 512;     // per-batch stride (token-major)

  wconv<<<1024, 256, 0, stream>>>(Wq, Wk, Wv, Wo, bq, bk, bv,
                                  wqkv, wqkv + 262144, wqkv + 524288, wob, bqkv);
  concat_tr<<<dim3(N_, 8, B_), 256, 0, stream>>>(x, tem, xin_tm);

  // Fused QKV: C[m][o] over o in [0,1536), dest selected per col-tile.
  gemm_bt<0><<<dim3(1020, 1, B_), 256, 0, stream>>>(xin_tm, 512, sBNT,
                                                    wqkv, 512, (size_t)0,
                                                    q_tm, 512, sBNT, E, bqkv, 512);

  attn<<<dim3(N_, KH_, B_), 256, 0, stream>>>(q_tm, k_tm, v_tm, ao_tm);

  // Y = relu(Wo . ao + bo), fp32 channel-major straight to d_out
  gemm_bt<2><<<dim3(340, 1, B_), 256, 0, stream>>>(wob, 512, (size_t)0,
                                                   ao_tm, 512, sBNT,
                                                   out, NT_, (size_t)512 * NT_, 0, bo, 512);
}